// Round 15
// baseline (245.872 us; speedup 1.0000x reference)
//
#include <hip/hip_runtime.h>
#include <stdint.h>
#include <math.h>

#define DEVI __device__ __forceinline__

typedef __attribute__((ext_vector_type(8))) short bf16x8;
typedef __attribute__((ext_vector_type(4))) float f32x4;

DEVI unsigned short f2bf(float f) {
  union { float f; unsigned u; } v; v.f = f;
  unsigned u = v.u;
  u += 0x7fffu + ((u >> 16) & 1u);   // round-to-nearest-even
  return (unsigned short)(u >> 16);
}

// pack two f32 -> one dword of 2x bf16 (lo = a, hi = b), RNE; no builtin on gfx950
DEVI unsigned cvt_pk_bf16(float a, float b) {
  unsigned r;
  asm("v_cvt_pk_bf16_f32 %0, %1, %2" : "=v"(r) : "v"(a), "v"(b));
  return r;
}

DEVI f32x4 mfma16(bf16x8 a, bf16x8 b, f32x4 c) {
  return __builtin_amdgcn_mfma_f32_16x16x32_bf16(a, b, c, 0, 0, 0);
}

// async global->LDS, 16 B per lane; LDS dest = wave-uniform base + lane*16
DEVI void gld16(const unsigned short* g, unsigned short* l) {
  __builtin_amdgcn_global_load_lds(
      (const __attribute__((address_space(1))) unsigned int*)(uintptr_t)g,
      (__attribute__((address_space(3))) unsigned int*)(unsigned int)(uintptr_t)l,
      16, 0, 0);
}

#define VMCNT(n) asm volatile("s_waitcnt vmcnt(" #n ")" ::: "memory")
#define BAR()                              \
  do {                                     \
    __builtin_amdgcn_s_barrier();          \
    __builtin_amdgcn_sched_barrier(0);     \
  } while (0)
// light barrier: seal LDS writes without draining vmcnt (attn)
#define LBAR()                                              \
  do {                                                      \
    asm volatile("s_waitcnt lgkmcnt(0)" ::: "memory");      \
    __builtin_amdgcn_s_barrier();                           \
    __builtin_amdgcn_sched_barrier(0);                      \
  } while (0)

template <int N> DEVI void vmcntc() {
  static_assert(N >= 0 && N <= 8, "");
  if constexpr (N == 0) VMCNT(0);
  else if constexpr (N == 1) VMCNT(1);
  else if constexpr (N == 2) VMCNT(2);
  else if constexpr (N == 3) VMCNT(3);
  else if constexpr (N == 4) VMCNT(4);
}

// ---------------- fp32 -> bf16 convert (3 buffers, 8 elems/thread) ----------
__global__ __launch_bounds__(256) void cvt3_kernel(
    const float* __restrict__ a, unsigned short* __restrict__ oa,
    const float* __restrict__ b, unsigned short* __restrict__ ob,
    const float* __restrict__ c, unsigned short* __restrict__ oc) {
  int bid = blockIdx.x;
  const float* in; unsigned short* out; int i;
  if (bid < 4096)      { in = a; out = oa; i = bid; }
  else if (bid < 5632) { in = b; out = ob; i = bid - 4096; }
  else                 { in = c; out = oc; i = bid - 5632; }
  int idx = (i * 256 + (int)threadIdx.x) * 8;
#pragma unroll
  for (int u = 0; u < 2; ++u) {
    float4 v = *(const float4*)(in + idx + u * 4);
    uint2 o;
    o.x = cvt_pk_bf16(v.x, v.y);
    o.y = cvt_pk_bf16(v.z, v.w);
    *(uint2*)(out + idx + u * 4) = o;
  }
}

// ======== 4-phase GEMM (r6-proven), generalized (MT, NTA, NTB) ========
// BM = MT*32, BN = 4*(NTA+NTB)*16; 8 waves (2M x 4N), wave tile (MT*16) x WTN.
// BK=64, XOR swizzle (0 conflicts), dbuf, 4-phase counted vmcnt, frag reuse.
// Per-thread staging unit sizes: Aa=Ab=AH=MT/4 chunks, Ba=NTA, Bb=NTB.
// Gates (FIFO ledger, re-derived): prologue/ph4 = NTB+AH; ph1 = 2*AH;
// ph2 = AH+NTA; peel = AH, 0.  (MT=8,NTA=2,NTB=1) reproduces r12 QKV exactly.
//   QKV:  <0,8,2,1>  BM=256,BN=192, grid 512 = 2 exact rounds, LDS 112KB.
//   proj: <1,4,1,1>  BM=128,BN=128, grid 512 = ONE co-resident round
//         (LDS 64KB -> 2 blocks/CU; r8 lesson: 1-block/CU gate stalls are
//          tile-size-independent; occupancy is the proj lever).
// MODE==0 writes Q,K as [b,h,t,d] and V TRANSPOSED as [b,h,d,t].
template <int MODE, int MT, int NTA, int NTB>
__global__ __launch_bounds__(512, 2) void gemm8(
    const unsigned short* __restrict__ A, const unsigned short* __restrict__ Bw,
    const float* __restrict__ bias, float* __restrict__ Cf,
    unsigned short* __restrict__ Qo, unsigned short* __restrict__ Ko,
    unsigned short* __restrict__ Vo, int M, int N, int K, int nbx) {
  constexpr int NTT = NTA + NTB;
  constexpr int WTN = NTT * 16;             // wave N-cols
  constexpr int BN = 4 * WTN;
  constexpr int BM = MT * 32;
  constexpr int AH = MT / 4;                // chunks per A unit per thread
  constexpr int A_USH = BM * 64;
  constexpr int B_USH = BN * 64;
  constexpr int BUFS = A_USH + B_USH;       // ushorts per buffer
  extern __shared__ unsigned short lds[];
  const int tid = threadIdx.x;
  const int lane = tid & 63;
  const int w = tid >> 6;                   // 0..7
  const int wm = w >> 2, wn = w & 3;
  const int lr = lane & 15, lq = lane >> 4;

  // T1: XCD-aware block swizzle (grid % 8 == 0 for both call sites)
  const int cpx = gridDim.x >> 3;
  const int swz = (blockIdx.x & 7) * cpx + (blockIdx.x >> 3);
  const int bx = swz % nbx, by = swz / nbx;
  const int m0 = by * BM, n0 = bx * BN;

  // staging source coords (swizzle baked into the per-lane global column)
  const int sr = lane >> 3;                       // 0..7 row within chunk
  const int sc = ((lane & 7) ^ sr) << 3;          // swizzled col element
  const unsigned short* pa = A + (size_t)(m0 + sr) * K + sc;
  const unsigned short* pb = Bw + (size_t)(n0 + sr) * K + sc;

  // fragment-read block swizzle offsets (ushorts); row&7 == lr&7 for all frags
  const int bs0 = (lq ^ (lr & 7)) << 3;
  const int bs1 = ((lq + 4) ^ (lr & 7)) << 3;

  f32x4 acc[MT][NTT] = {};

  auto sA = [&](int buf, int kt, int c) {
    gld16(pa + (size_t)(c << 3) * K + kt, lds + buf * BUFS + (c << 9));
  };
  auto sB = [&](int buf, int kt, int c) {
    gld16(pb + (size_t)(c << 3) * K + kt, lds + buf * BUFS + A_USH + (c << 9));
  };
  // A units (chunk = 8 rows = 1KB): A_a = mh0 rows of both wm-halves; A_b comp.
  const int aA0 = (MT == 8) ? w : ((w & 3) + ((w >> 2) << 3));
  const int aB0 = (MT == 8) ? (8 + w) : (aA0 + 4);
  auto sAa = [&](int buf, int kt) {
    sA(buf, kt, aA0);
    if constexpr (MT == 8) sA(buf, kt, 16 + w);
  };
  auto sAb = [&](int buf, int kt) {
    sA(buf, kt, aB0);
    if constexpr (MT == 8) sA(buf, kt, 24 + w);
  };
  auto sBa = [&](int buf, int kt) {
#pragma unroll
    for (int k2 = 0; k2 < NTA; ++k2)
      sB(buf, kt, (w & 3) * NTT * 2 + (w >> 2) * NTA + k2);
  };
  auto sBb = [&](int buf, int kt) {
#pragma unroll
    for (int k2 = 0; k2 < NTB; ++k2)
      sB(buf, kt, (w & 3) * NTT * 2 + NTA * 2 + (w >> 2) * NTB + k2);
  };

#define LDA(A_, mh)                                                          \
  _Pragma("unroll") for (int i = 0; i < MT / 2; ++i) {                       \
    int ar = wm * (BM / 2) + (mh) * (BM / 4) + i * 16 + lr;                  \
    A_[i][0] = *(const bf16x8*)(As_ + ar * 64 + bs0);                        \
    A_[i][1] = *(const bf16x8*)(As_ + ar * 64 + bs1);                        \
  }
#define LDB(B_, CNT, ntb)                                                    \
  _Pragma("unroll") for (int j = 0; j < (CNT); ++j) {                        \
    int br = wn * WTN + ((ntb) + j) * 16 + lr;                               \
    B_[j][0] = *(const bf16x8*)(Bs_ + br * 64 + bs0);                        \
    B_[j][1] = *(const bf16x8*)(Bs_ + br * 64 + bs1);                        \
  }
#define MM(A_, B_, mh, CNT, ntb)                                             \
  __builtin_amdgcn_s_setprio(1);                                             \
  _Pragma("unroll") for (int i = 0; i < MT / 2; ++i)                         \
    _Pragma("unroll") for (int j = 0; j < (CNT); ++j) {                      \
      acc[(mh) * (MT / 2) + i][(ntb) + j] = mfma16(                          \
          A_[i][0], B_[j][0], acc[(mh) * (MT / 2) + i][(ntb) + j]);          \
      acc[(mh) * (MT / 2) + i][(ntb) + j] = mfma16(                          \
          A_[i][1], B_[j][1], acc[(mh) * (MT / 2) + i][(ntb) + j]);          \
    }                                                                        \
  __builtin_amdgcn_s_setprio(0);

  // prologue: tile 0 into buf0 (unit order A_a, B_a, B_b, A_b)
  sAa(0, 0); sBa(0, 0); sBb(0, 0); sAb(0, 0);
  vmcntc<NTB + AH>();                // A_a(0), B_a(0) landed
  BAR();

  const int NT = K >> 6;
  for (int t = 0; t < NT - 1; ++t) {
    const int buf = t & 1, nb = buf ^ 1;
    const int kt = (t + 1) << 6;
    const unsigned short* As_ = lds + buf * BUFS;
    const unsigned short* Bs_ = As_ + A_USH;
    bf16x8 af[MT / 2][2], baf[NTA][2], bbf[NTB][2];
    // ph1: quadrant (0,a); stage A_a(t+1)
    sAa(nb, kt);
    LDA(af, 0); LDB(baf, NTA, 0);
    MM(af, baf, 0, NTA, 0);
    vmcntc<2 * AH>(); BAR();         // B_b(t) landed for all waves
    // ph2: (0,b); stage B_a(t+1); reuse A0
    sBa(nb, kt);
    LDB(bbf, NTB, NTA);
    MM(af, bbf, 0, NTB, NTA);
    vmcntc<AH + NTA>(); BAR();       // A_b(t) landed for all waves
    // ph3: (1,b); stage B_b(t+1); reuse Bb, load A1 (A0 dead)
    sBb(nb, kt);
    LDA(af, 1);
    MM(af, bbf, 1, NTB, NTA);
    // ph4: (1,a); stage A_b(t+1); reuse A1 and Ba — zero ds_reads
    sAb(nb, kt);
    MM(af, baf, 1, NTA, 0);
    vmcntc<NTB + AH>(); BAR();       // A_a(t+1), B_a(t+1) landed
  }
  { // peeled last tile (no staging; same phase order, tighter gates)
    const int buf = (NT - 1) & 1;
    const unsigned short* As_ = lds + buf * BUFS;
    const unsigned short* Bs_ = As_ + A_USH;
    bf16x8 af[MT / 2][2], baf[NTA][2], bbf[NTB][2];
    LDA(af, 0); LDB(baf, NTA, 0);
    MM(af, baf, 0, NTA, 0);
    vmcntc<AH>(); BAR();             // B_b(last) landed
    LDB(bbf, NTB, NTA);
    MM(af, bbf, 0, NTB, NTA);
    vmcntc<0>(); BAR();              // A_b(last) landed
    LDA(af, 1);
    MM(af, bbf, 1, NTB, NTA);
    MM(af, baf, 1, NTA, 0);
  }
#undef LDA
#undef LDB
#undef MM

  // epilogue (wave tile (MT*16) x WTN)
#pragma unroll
  for (int mt = 0; mt < MT; ++mt) {
#pragma unroll
    for (int nt = 0; nt < NTT; ++nt) {
      int n_g = n0 + wn * WTN + nt * 16 + lr;
      float bv = bias[n_g];
      if (MODE == 1) {
#pragma unroll
        for (int r = 0; r < 4; ++r) {
          int m_g = m0 + wm * (BM / 2) + mt * 16 + lq * 4 + r;
          Cf[(size_t)m_g * N + n_g] = acc[mt][nt][r] + bv;
        }
      } else {
        int which = n_g >> 10;               // 0:Q 1:K 2:V (wave-uniform)
        int rem = n_g & 1023;
        int h = rem >> 6, d = rem & 63;
        int m_base = m0 + wm * (BM / 2) + mt * 16 + lq * 4;
        int b = m_base >> 11, tt = m_base & 2047;
        if (which == 2) {
          uint2 pv;
          pv.x = cvt_pk_bf16(acc[mt][nt][0] + bv, acc[mt][nt][1] + bv);
          pv.y = cvt_pk_bf16(acc[mt][nt][2] + bv, acc[mt][nt][3] + bv);
          *(uint2*)(Vo + (((size_t)(b * 16 + h) * 64 + d) * 2048 + tt)) = pv;
        } else {
          unsigned short* p = (which == 0) ? Qo : Ko;
#pragma unroll
          for (int r = 0; r < 4; ++r) {
            size_t idx = (((size_t)(b * 16 + h) * 2048) + tt + r) * 64 + d;
            p[idx] = f2bf(acc[mt][nt][r] + bv);
          }
        }
      }
    }
  }
}

// ------- flash attention (causal), S^T formulation, 256-row Q-tiles -------
// r12 structure + LBAR (r14). Round-15 fix: Pt row stride 72 -> 68 ushorts.
// Quarter-wave bank audit: at stride 72 (36 dwords) the b64 Pt-write start
// bank = 4*(lr&7)+2lq -> lr / lr+8 collide -> 2cy/quarter -> +4cy/instr,
// matching the measured 7.57M SQ_LDS_BANK_CONFLICT. Stride 68 (34 dwords):
// start = 2*lr (+const) = 16 DISTINCT banks -> conflict-free. 68-ush rows are
// 8B-aligned only, so pf reads are 2x uint2 (same cycles as b128); the
// sched_barrier between them prevents fusing into a misaligned b128.
__global__ __launch_bounds__(512, 2) void attn_kernel(
    const unsigned short* __restrict__ Q, const unsigned short* __restrict__ K,
    const unsigned short* __restrict__ V, unsigned short* __restrict__ Y) {
  constexpr int T = 2048, HD = 64, H = 16;
  __shared__ unsigned short Kt[2][64 * 72];   // K rows [kv][d], pad 8
  __shared__ unsigned short Vt[2][64 * 72];   // V^T    [d][kv], pad 8
  __shared__ unsigned short Pt[8][16 * 68];   // per-wave P, [q][kv], stride 68

  const int tid = threadIdx.x;
  const int lane = tid & 63;
  const int w = tid >> 6;                     // 0..7
  const int lr = lane & 15, lq = lane >> 4;
  const int pair = blockIdx.x;                // 0..3
  const int h = blockIdx.y;
  const int b = blockIdx.z;
  const size_t bh = (size_t)(b * H + h) * T * HD;   // also V^T base (64*2048)
  const float SC = 0.125f * 1.44269504089f;   // 1/sqrt(64) * log2(e)

  const int krow = tid >> 3, kcb = (tid & 7) << 3;  // 64 rows x 64 cols tile

  float4 kr, vr;
  auto load_tile = [&](int jt) {
    const int c0 = jt * 64;
    kr = *(const float4*)(K + bh + (size_t)(c0 + krow) * HD + kcb);
    vr = *(const float4*)(V + bh + (size_t)krow * T + c0 + kcb);  // V^T row=d
  };
  auto stage = [&](int buf) {
    *(float4*)(&Kt[buf][krow * 72 + kcb]) = kr;
    *(float4*)(&Vt[buf][krow * 72 + kcb]) = vr;
  };

  load_tile(0);

  for (int phase = 0; phase < 2; ++phase) {
    const int qt = phase ? (7 - pair) : pair;
    const int q0 = qt * 256;
    const int nkv = 4 * (qt + 1);
    const int qw = q0 + w * 32;          // wave's first q-row

    bf16x8 qf[2][2];
#pragma unroll
    for (int qs = 0; qs < 2; ++qs)
#pragma unroll
      for (int kb = 0; kb < 2; ++kb)
        qf[qs][kb] = *(const bf16x8*)(Q + bh + (size_t)(qw + qs * 16 + lr) * HD +
                                      kb * 32 + lq * 8);

    f32x4 o[2][4] = {};
    float mi[2] = {-INFINITY, -INFINITY}, li[2] = {0.f, 0.f};

    stage(0);
    load_tile(1);
    LBAR();

    for (int jt = 0; jt < nkv; ++jt) {
      const int c0 = jt * 64;
      const int buf = jt & 1;

      if (c0 <= qw + 31) {               // wave-uniform: else tile fully masked
        // S^T = K Q^T : rows kv, cols q (K frags shared across qs)
        f32x4 s[2][4];
        __builtin_amdgcn_s_setprio(1);
#pragma unroll
        for (int nt = 0; nt < 4; ++nt) {
          bf16x8 kf0 = *(const bf16x8*)(&Kt[buf][(nt * 16 + lr) * 72 + lq * 8]);
          bf16x8 kf1 = *(const bf16x8*)(&Kt[buf][(nt * 16 + lr) * 72 + 32 + lq * 8]);
#pragma unroll
          for (int qs = 0; qs < 2; ++qs) {
            f32x4 z = {};
            z = mfma16(kf0, qf[qs][0], z);
            s[qs][nt] = mfma16(kf1, qf[qs][1], z);
          }
        }
        __builtin_amdgcn_s_setprio(0);
        // causal mask (raw domain), diagonal-adjacent tiles only
        if (c0 + 63 > qw) {
#pragma unroll
          for (int qs = 0; qs < 2; ++qs) {
            int qg = qw + qs * 16 + lr;
#pragma unroll
            for (int nt = 0; nt < 4; ++nt)
#pragma unroll
              for (int r = 0; r < 4; ++r) {
                int kvg = c0 + nt * 16 + lq * 4 + r;
                if (kvg > qg) s[qs][nt][r] = -INFINITY;
              }
          }
        }
        // online softmax (scaled domain), T13 defer-max THR=8
        float mxs[2];
#pragma unroll
        for (int qs = 0; qs < 2; ++qs) {
          float mx = -INFINITY;
#pragma unroll
          for (int nt = 0; nt < 4; ++nt)
            mx = fmaxf(mx, fmaxf(fmaxf(s[qs][nt][0], s[qs][nt][1]),
                                 fmaxf(s[qs][nt][2], s[qs][nt][3])));
          mx = fmaxf(mx, __shfl_xor(mx, 16));
          mx = fmaxf(mx, __shfl_xor(mx, 32));
          mxs[qs] = mx * SC;
        }
        if (!__all((mxs[0] <= mi[0] + 8.f) && (mxs[1] <= mi[1] + 8.f))) {
#pragma unroll
          for (int qs = 0; qs < 2; ++qs) {
            float mnew = fmaxf(mi[qs], mxs[qs]);
            float alpha = __builtin_amdgcn_exp2f(mi[qs] - mnew);
            mi[qs] = mnew;
            li[qs] *= alpha;
#pragma unroll
            for (int nt = 0; nt < 4; ++nt)
#pragma unroll
              for (int r = 0; r < 4; ++r) o[qs][nt][r] *= alpha;
          }
        }
        // P = exp2(s*SC - mi) -> per-wave Pt (stride 68) -> B-frag regs;
        // one 16-row Pt buffer reused across qs (in-wave LDS ordering).
        bf16x8 pf[2][2];
#pragma unroll
        for (int qs = 0; qs < 2; ++qs) {
          float rs = 0.f;
#pragma unroll
          for (int nt = 0; nt < 4; ++nt) {
            float p0 = __builtin_amdgcn_exp2f(fmaf(s[qs][nt][0], SC, -mi[qs]));
            float p1 = __builtin_amdgcn_exp2f(fmaf(s[qs][nt][1], SC, -mi[qs]));
            float p2 = __builtin_amdgcn_exp2f(fmaf(s[qs][nt][2], SC, -mi[qs]));
            float p3 = __builtin_amdgcn_exp2f(fmaf(s[qs][nt][3], SC, -mi[qs]));
            rs += (p0 + p1) + (p2 + p3);
            uint2 pk;
            pk.x = cvt_pk_bf16(p0, p1);
            pk.y = cvt_pk_bf16(p2, p3);
            *(uint2*)(&Pt[w][lr * 68 + nt * 16 + lq * 4]) = pk;
          }
          li[qs] += rs;                  // per-lane partial; reduced at end
#pragma unroll
          for (int kb = 0; kb < 2; ++kb) {
            union { uint2 u[2]; bf16x8 v; } pu;
            pu.u[0] = *(const uint2*)(&Pt[w][lr * 68 + kb * 32 + lq * 8]);
            __builtin_amdgcn_sched_barrier(0);
            pu.u[1] = *(const uint2*)(&Pt[w][lr * 68 + kb * 32 + lq * 8 + 4]);
            pf[qs][kb] = pu.v;
          }
        }
        // O^T += V^T P^T (V frags read once, used for both qs)
        __builtin_amdgcn_s_setprio(1);
#pragma unroll
        for (int nt = 0; nt < 4; ++nt) {
          bf16x8 vf0 = *(const bf16x8*)(&Vt[buf][(nt * 16 + lr) * 72 + lq * 8]);
          bf16x8 vf1 = *(const bf16x8*)(&Vt[buf][(nt * 16 + lr) * 72 + 32 + lq * 8]);
#pragma unroll
          for (int qs = 0; qs < 2; ++qs) {
            o[qs][nt] = mfma16(vf0, pf[qs][0], o[qs][nt]);
            o[qs][nt] = mfma16(vf1, pf[qs][1], o[qs][nt]);
          }
        }
        __builtin_amdgcn_s_setprio(0);
      }

      if (jt + 1 < nkv) {
        stage(buf ^ 1);
        if (jt + 2 < nkv) load_tile(jt + 2);
        else if (phase == 0) load_tile(0);
        LBAR();
      }
    }

    // epilogue: reduce per-lane li over lq groups, write Y
#pragma unroll
    for (int qs = 0; qs < 2; ++qs) {
      float l = li[qs];
      l += __shfl_xor(l, 16);
      l += __shfl_xor(l, 32);
      float inv = 1.f / l;
      int t_g = qw + qs * 16 + lr;
#pragma unroll
      for (int nt = 0; nt < 4; ++nt) {
        uint2 yv;
        yv.x = cvt_pk_bf16(o[qs][nt][0] * inv, o[qs][nt][1] * inv);
        yv.y = cvt_pk_bf16(o[qs][nt][2] * inv, o[qs][nt][3] * inv);
        *(uint2*)(Y + ((size_t)(b * T + t_g)) * 1024 + h * 64 + nt * 16 + lq * 4) = yv;
      }
    }
  }
}

// ---------------- launch ----------------
extern "C" void kernel_launch(void* const* d_in, const int* in_sizes, int n_in,
                              void* d_out, int out_size, void* d_ws, size_t ws_size,
                              hipStream_t stream) {
  const float* x = (const float*)d_in[0];       // [4,2048,1024]
  const float* qkv_w = (const float*)d_in[1];   // [3072,1024]
  const float* qkv_b = (const float*)d_in[2];   // [3072]
  const float* proj_w = (const float*)d_in[3];  // [1024,1024]
  const float* proj_b = (const float*)d_in[4];  // [1024]
  float* out = (float*)d_out;                   // [4,2048,1024] fp32

  unsigned short* ws = (unsigned short*)d_ws;
  unsigned short* xb = ws;                     // 8388608
  unsigned short* wqkv = xb + 8388608;         // 3145728
  unsigned short* wproj = wqkv + 3145728;      // 1048576
  unsigned short* Qb = wproj + 1048576;        // 8388608 [B,H,T,hd]
  unsigned short* Kb = Qb + 8388608;           // 8388608 [B,H,T,hd]
  unsigned short* Vb = Kb + 8388608;           // 8388608 [B,H,hd,T] (transposed!)
  unsigned short* Yb = Vb + 8388608;           // 8388608 [B*T, C]

  auto* g0 = gemm8<0, 8, 2, 1>;
  auto* g1 = gemm8<1, 4, 1, 1>;
  static bool attr_set = false;
  if (!attr_set) {
    (void)hipFuncSetAttribute((const void*)g0,
                              hipFuncAttributeMaxDynamicSharedMemorySize, 114688);
    (void)hipFuncSetAttribute((const void*)g1,
                              hipFuncAttributeMaxDynamicSharedMemorySize, 65536);
    attr_set = true;
  }

  cvt3_kernel<<<6144, 256, 0, stream>>>(x, xb, qkv_w, wqkv, proj_w, wproj);

  // QKV: M=8192, N=3072, K=1024, BM=256/BN=192 -> grid 32*16=512 (2 EXACT rounds)
  gemm8<0, 8, 2, 1><<<dim3(512), 512, 114688, stream>>>(xb, wqkv, qkv_b, nullptr,
                                                        Qb, Kb, Vb, 8192, 3072,
                                                        1024, 16);
  // attn: grid 256 (pair, h, b)
  attn_kernel<<<dim3(4, 16, 4), 512, 0, stream>>>(Qb, Kb, Vb, Yb);
  // proj: M=8192, N=1024, K=1024, BM=128/BN=128 -> grid 64*8=512, 64KB LDS
  // -> 2 blocks/CU, ONE co-resident round
  gemm8<1, 4, 1, 1><<<dim3(512), 512, 65536, stream>>>(Yb, wproj, proj_b, out,
                                                       nullptr, nullptr, nullptr,
                                                       8192, 1024, 1024, 8);
}

// Round 16
// 242.224 us; speedup vs baseline: 1.0151x; 1.0151x over previous
//
#include <hip/hip_runtime.h>
#include <stdint.h>
#include <math.h>

#define DEVI __device__ __forceinline__

typedef __attribute__((ext_vector_type(8))) short bf16x8;
typedef __attribute__((ext_vector_type(4))) float f32x4;

DEVI unsigned short f2bf(float f) {
  union { float f; unsigned u; } v; v.f = f;
  unsigned u = v.u;
  u += 0x7fffu + ((u >> 16) & 1u);   // round-to-nearest-even
  return (unsigned short)(u >> 16);
}

// pack two f32 -> one dword of 2x bf16 (lo = a, hi = b), RNE; no builtin on gfx950
DEVI unsigned cvt_pk_bf16(float a, float b) {
  unsigned r;
  asm("v_cvt_pk_bf16_f32 %0, %1, %2" : "=v"(r) : "v"(a), "v"(b));
  return r;
}

DEVI f32x4 mfma16(bf16x8 a, bf16x8 b, f32x4 c) {
  return __builtin_amdgcn_mfma_f32_16x16x32_bf16(a, b, c, 0, 0, 0);
}

// async global->LDS, 16 B per lane; LDS dest = wave-uniform base + lane*16
DEVI void gld16(const unsigned short* g, unsigned short* l) {
  __builtin_amdgcn_global_load_lds(
      (const __attribute__((address_space(1))) unsigned int*)(uintptr_t)g,
      (__attribute__((address_space(3))) unsigned int*)(unsigned int)(uintptr_t)l,
      16, 0, 0);
}

#define VMCNT(n) asm volatile("s_waitcnt vmcnt(" #n ")" ::: "memory")
#define BAR()                              \
  do {                                     \
    __builtin_amdgcn_s_barrier();          \
    __builtin_amdgcn_sched_barrier(0);     \
  } while (0)

template <int N> DEVI void vmcntc() {
  static_assert(N >= 0 && N <= 8, "");
  if constexpr (N == 0) VMCNT(0);
  else if constexpr (N == 2) VMCNT(2);
  else if constexpr (N == 3) VMCNT(3);
  else if constexpr (N == 4) VMCNT(4);
}

// ---------------- fp32 -> bf16 convert (3 buffers, one launch) ----------------
__global__ __launch_bounds__(256) void cvt3_kernel(
    const float* __restrict__ a, unsigned short* __restrict__ oa,
    const float* __restrict__ b, unsigned short* __restrict__ ob,
    const float* __restrict__ c, unsigned short* __restrict__ oc) {
  int bid = blockIdx.x;
  const float* in; unsigned short* out; int i;
  if (bid < 8192)       { in = a; out = oa; i = bid; }
  else if (bid < 11264) { in = b; out = ob; i = bid - 8192; }
  else                  { in = c; out = oc; i = bid - 11264; }
  int idx = (i * 256 + (int)threadIdx.x) * 4;
  float4 v = *(const float4*)(in + idx);
  unsigned lo = f2bf(v.x) | ((unsigned)f2bf(v.y) << 16);
  unsigned hi = f2bf(v.z) | ((unsigned)f2bf(v.w) << 16);
  uint2 o; o.x = lo; o.y = hi;
  *(uint2*)(out + idx) = o;
}

// ======== 4-phase GEMM (r6-proven), exact-round grids (r12, verbatim) ======
// BK=64, XOR swizzle (0 conflicts), dbuf, 4-phase counted vmcnt, fragment
// reuse. QKV (2,1): BN=192, grid 512 = 2 exact rounds. proj (1,1): BN=128,
// grid 256 = 1 exact round.
// MODE==0 writes Q,K as [b,h,t,d] and V TRANSPOSED as [b,h,d,t].
template <int MODE, int NTA, int NTB>
__global__ __launch_bounds__(512, 2) void gemm8(
    const unsigned short* __restrict__ A, const unsigned short* __restrict__ Bw,
    const float* __restrict__ bias, float* __restrict__ Cf,
    unsigned short* __restrict__ Qo, unsigned short* __restrict__ Ko,
    unsigned short* __restrict__ Vo, int M, int N, int K, int nbx) {
  constexpr int NTT = NTA + NTB;
  constexpr int WTN = NTT * 16;             // wave N-cols
  constexpr int BN = 4 * WTN;
  constexpr int B_USH = BN * 64;
  constexpr int BUFS = 16384 + B_USH;       // A 32KB + B per buffer (ushorts)
  extern __shared__ unsigned short lds[];
  const int tid = threadIdx.x;
  const int lane = tid & 63;
  const int w = tid >> 6;                   // 0..7
  const int wm = w >> 2, wn = w & 3;
  const int lr = lane & 15, lq = lane >> 4;

  // T1: XCD-aware block swizzle (grid % 8 == 0 for both call sites)
  const int cpx = gridDim.x >> 3;
  const int swz = (blockIdx.x & 7) * cpx + (blockIdx.x >> 3);
  const int bx = swz % nbx, by = swz / nbx;
  const int m0 = by * 256, n0 = bx * BN;

  // staging source coords (swizzle baked into the per-lane global column)
  const int sr = lane >> 3;                       // 0..7 row within chunk
  const int sc = ((lane & 7) ^ sr) << 3;          // swizzled col element
  const unsigned short* pa = A + (size_t)(m0 + sr) * K + sc;
  const unsigned short* pb = Bw + (size_t)(n0 + sr) * K + sc;

  // fragment-read block swizzle offsets (ushorts); row&7 == lr&7 for all frags
  const int bs0 = (lq ^ (lr & 7)) << 3;
  const int bs1 = ((lq + 4) ^ (lr & 7)) << 3;

  f32x4 acc[8][NTT] = {};

  auto sA = [&](int buf, int kt, int c) {
    gld16(pa + (size_t)(c << 3) * K + kt, lds + buf * BUFS + (c << 9));
  };
  auto sB = [&](int buf, int kt, int c) {
    gld16(pb + (size_t)(c << 3) * K + kt, lds + buf * BUFS + 16384 + (c << 9));
  };
  auto sAa = [&](int buf, int kt) { sA(buf, kt, w); sA(buf, kt, 16 + w); };
  auto sAb = [&](int buf, int kt) { sA(buf, kt, 8 + w); sA(buf, kt, 24 + w); };
  auto sBa = [&](int buf, int kt) {
#pragma unroll
    for (int k2 = 0; k2 < NTA; ++k2)
      sB(buf, kt, (w & 3) * NTT * 2 + (w >> 2) * NTA + k2);
  };
  auto sBb = [&](int buf, int kt) {
#pragma unroll
    for (int k2 = 0; k2 < NTB; ++k2)
      sB(buf, kt, (w & 3) * NTT * 2 + NTA * 2 + (w >> 2) * NTB + k2);
  };

#define LDA(A_, mh)                                                          \
  _Pragma("unroll") for (int i = 0; i < 4; ++i) {                            \
    int ar = wm * 128 + (mh) * 64 + i * 16 + lr;                             \
    A_[i][0] = *(const bf16x8*)(As_ + ar * 64 + bs0);                        \
    A_[i][1] = *(const bf16x8*)(As_ + ar * 64 + bs1);                        \
  }
#define LDB(B_, CNT, ntb)                                                    \
  _Pragma("unroll") for (int j = 0; j < (CNT); ++j) {                        \
    int br = wn * WTN + ((ntb) + j) * 16 + lr;                               \
    B_[j][0] = *(const bf16x8*)(Bs_ + br * 64 + bs0);                        \
    B_[j][1] = *(const bf16x8*)(Bs_ + br * 64 + bs1);                        \
  }
#define MM(A_, B_, mh, CNT, ntb)                                             \
  __builtin_amdgcn_s_setprio(1);                                             \
  _Pragma("unroll") for (int i = 0; i < 4; ++i)                              \
    _Pragma("unroll") for (int j = 0; j < (CNT); ++j) {                      \
      acc[(mh) * 4 + i][(ntb) + j] =                                         \
          mfma16(A_[i][0], B_[j][0], acc[(mh) * 4 + i][(ntb) + j]);          \
      acc[(mh) * 4 + i][(ntb) + j] =                                         \
          mfma16(A_[i][1], B_[j][1], acc[(mh) * 4 + i][(ntb) + j]);          \
    }                                                                        \
  __builtin_amdgcn_s_setprio(0);

  // prologue: tile 0 into buf0 (unit order A_a, B_a, B_b, A_b)
  sAa(0, 0); sBa(0, 0); sBb(0, 0); sAb(0, 0);
  vmcntc<NTB + 2>();                 // A_a(0), B_a(0) landed
  BAR();

  const int NT = K >> 6;
  for (int t = 0; t < NT - 1; ++t) {
    const int buf = t & 1, nb = buf ^ 1;
    const int kt = (t + 1) << 6;
    const unsigned short* As_ = lds + buf * BUFS;
    const unsigned short* Bs_ = As_ + 16384;
    bf16x8 af[4][2], baf[NTA][2], bbf[NTB][2];
    // ph1: quadrant (0,a); stage A_a(t+1)
    sAa(nb, kt);
    LDA(af, 0); LDB(baf, NTA, 0);
    MM(af, baf, 0, NTA, 0);
    vmcntc<4>(); BAR();              // B_b(t) landed for all waves
    // ph2: (0,b); stage B_a(t+1); reuse A0
    sBa(nb, kt);
    LDB(bbf, NTB, NTA);
    MM(af, bbf, 0, NTB, NTA);
    vmcntc<NTA + 2>(); BAR();        // A_b(t) landed for all waves
    // ph3: (1,b); stage B_b(t+1); reuse Bb, load A1 (A0 dead)
    sBb(nb, kt);
    LDA(af, 1);
    MM(af, bbf, 1, NTB, NTA);
    // ph4: (1,a); stage A_b(t+1); reuse A1 and Ba — zero ds_reads
    sAb(nb, kt);
    MM(af, baf, 1, NTA, 0);
    vmcntc<NTB + 2>(); BAR();        // A_a(t+1), B_a(t+1) landed
  }
  { // peeled last tile (no staging; same phase order, tighter gates)
    const int buf = (NT - 1) & 1;
    const unsigned short* As_ = lds + buf * BUFS;
    const unsigned short* Bs_ = As_ + 16384;
    bf16x8 af[4][2], baf[NTA][2], bbf[NTB][2];
    LDA(af, 0); LDB(baf, NTA, 0);
    MM(af, baf, 0, NTA, 0);
    vmcntc<2>(); BAR();              // B_b(last) landed
    LDB(bbf, NTB, NTA);
    MM(af, bbf, 0, NTB, NTA);
    vmcntc<0>(); BAR();              // A_b(last) landed
    LDA(af, 1);
    MM(af, bbf, 1, NTB, NTA);
    MM(af, baf, 1, NTA, 0);
  }
#undef LDA
#undef LDB
#undef MM

  // epilogue (wave tile 128 x WTN)
#pragma unroll
  for (int mt = 0; mt < 8; ++mt) {
#pragma unroll
    for (int nt = 0; nt < NTT; ++nt) {
      int n_g = n0 + wn * WTN + nt * 16 + lr;
      float bv = bias[n_g];
      if (MODE == 1) {
#pragma unroll
        for (int r = 0; r < 4; ++r) {
          int m_g = m0 + wm * 128 + mt * 16 + lq * 4 + r;
          Cf[(size_t)m_g * N + n_g] = acc[mt][nt][r] + bv;
        }
      } else {
        int which = n_g >> 10;               // 0:Q 1:K 2:V (wave-uniform)
        int rem = n_g & 1023;
        int h = rem >> 6, d = rem & 63;
        int m_base = m0 + wm * 128 + mt * 16 + lq * 4;
        int b = m_base >> 11, tt = m_base & 2047;
        if (which == 2) {
          uint2 pv;
          pv.x = cvt_pk_bf16(acc[mt][nt][0] + bv, acc[mt][nt][1] + bv);
          pv.y = cvt_pk_bf16(acc[mt][nt][2] + bv, acc[mt][nt][3] + bv);
          *(uint2*)(Vo + (((size_t)(b * 16 + h) * 64 + d) * 2048 + tt)) = pv;
        } else {
          unsigned short* p = (which == 0) ? Qo : Ko;
#pragma unroll
          for (int r = 0; r < 4; ++r) {
            size_t idx = (((size_t)(b * 16 + h) * 2048) + tt + r) * 64 + d;
            p[idx] = f2bf(acc[mt][nt][r] + bv);
          }
        }
      }
    }
  }
}

// ------- flash attention (causal), S^T formulation, 256-row Q-tiles -------
// r12 structure verbatim, with ONE change: Pt row stride 72 -> 68 ushorts.
// Quarter-wave bank audit: at stride 72 the b64 Pt-write start bank =
// 4*(lr&7)+2lq -> lanes lr and lr+8 collide -> 2cy/quarter -> +4cy/instr
// x 8 writes x 8 waves x 36 iters x 256 blocks ~= the measured 7.57M
// SQ_LDS_BANK_CONFLICT. Stride 68: start bank = 2*lr (+const) = 16 DISTINCT
// banks -> conflict-free. 68-ush rows are 8B-aligned only, so pf reads are
// 2x uint2 (same cycles as b128); sched_barrier(0) prevents fusing them
// into a misaligned b128.
__global__ __launch_bounds__(512, 2) void attn_kernel(
    const unsigned short* __restrict__ Q, const unsigned short* __restrict__ K,
    const unsigned short* __restrict__ V, unsigned short* __restrict__ Y) {
  constexpr int T = 2048, HD = 64, H = 16;
  __shared__ unsigned short Kt[2][64 * 72];   // K rows [kv][d], pad 8
  __shared__ unsigned short Vt[2][64 * 72];   // V^T    [d][kv], pad 8
  __shared__ unsigned short Pt[8][16 * 68];   // per-wave P, [q][kv], stride 68

  const int tid = threadIdx.x;
  const int lane = tid & 63;
  const int w = tid >> 6;                     // 0..7
  const int lr = lane & 15, lq = lane >> 4;
  const int pair = blockIdx.x;                // 0..3
  const int h = blockIdx.y;
  const int b = blockIdx.z;
  const size_t bh = (size_t)(b * H + h) * T * HD;   // also V^T base (64*2048)
  const float SC = 0.125f * 1.44269504089f;   // 1/sqrt(64) * log2(e)

  const int krow = tid >> 3, kcb = (tid & 7) << 3;  // 64 rows x 64 cols tile

  float4 kr, vr;
  auto load_tile = [&](int jt) {
    const int c0 = jt * 64;
    kr = *(const float4*)(K + bh + (size_t)(c0 + krow) * HD + kcb);
    vr = *(const float4*)(V + bh + (size_t)krow * T + c0 + kcb);  // V^T row=d
  };
  auto stage = [&](int buf) {
    *(float4*)(&Kt[buf][krow * 72 + kcb]) = kr;
    *(float4*)(&Vt[buf][krow * 72 + kcb]) = vr;
  };

  load_tile(0);

  for (int phase = 0; phase < 2; ++phase) {
    const int qt = phase ? (7 - pair) : pair;
    const int q0 = qt * 256;
    const int nkv = 4 * (qt + 1);
    const int qw = q0 + w * 32;          // wave's first q-row

    bf16x8 qf[2][2];
#pragma unroll
    for (int qs = 0; qs < 2; ++qs)
#pragma unroll
      for (int kb = 0; kb < 2; ++kb)
        qf[qs][kb] = *(const bf16x8*)(Q + bh + (size_t)(qw + qs * 16 + lr) * HD +
                                      kb * 32 + lq * 8);

    f32x4 o[2][4] = {};
    float mi[2] = {-INFINITY, -INFINITY}, li[2] = {0.f, 0.f};

    stage(0);
    load_tile(1);
    __syncthreads();

    for (int jt = 0; jt < nkv; ++jt) {
      const int c0 = jt * 64;
      const int buf = jt & 1;

      if (c0 <= qw + 31) {               // wave-uniform: else tile fully masked
        // S^T = K Q^T : rows kv, cols q (K frags shared across qs)
        f32x4 s[2][4];
        __builtin_amdgcn_s_setprio(1);
#pragma unroll
        for (int nt = 0; nt < 4; ++nt) {
          bf16x8 kf0 = *(const bf16x8*)(&Kt[buf][(nt * 16 + lr) * 72 + lq * 8]);
          bf16x8 kf1 = *(const bf16x8*)(&Kt[buf][(nt * 16 + lr) * 72 + 32 + lq * 8]);
#pragma unroll
          for (int qs = 0; qs < 2; ++qs) {
            f32x4 z = {};
            z = mfma16(kf0, qf[qs][0], z);
            s[qs][nt] = mfma16(kf1, qf[qs][1], z);
          }
        }
        __builtin_amdgcn_s_setprio(0);
        // causal mask (raw domain), diagonal-adjacent tiles only
        if (c0 + 63 > qw) {
#pragma unroll
          for (int qs = 0; qs < 2; ++qs) {
            int qg = qw + qs * 16 + lr;
#pragma unroll
            for (int nt = 0; nt < 4; ++nt)
#pragma unroll
              for (int r = 0; r < 4; ++r) {
                int kvg = c0 + nt * 16 + lq * 4 + r;
                if (kvg > qg) s[qs][nt][r] = -INFINITY;
              }
          }
        }
        // online softmax (scaled domain), T13 defer-max THR=8
        float mxs[2];
#pragma unroll
        for (int qs = 0; qs < 2; ++qs) {
          float mx = -INFINITY;
#pragma unroll
          for (int nt = 0; nt < 4; ++nt)
            mx = fmaxf(mx, fmaxf(fmaxf(s[qs][nt][0], s[qs][nt][1]),
                                 fmaxf(s[qs][nt][2], s[qs][nt][3])));
          mx = fmaxf(mx, __shfl_xor(mx, 16));
          mx = fmaxf(mx, __shfl_xor(mx, 32));
          mxs[qs] = mx * SC;
        }
        if (!__all((mxs[0] <= mi[0] + 8.f) && (mxs[1] <= mi[1] + 8.f))) {
#pragma unroll
          for (int qs = 0; qs < 2; ++qs) {
            float mnew = fmaxf(mi[qs], mxs[qs]);
            float alpha = __builtin_amdgcn_exp2f(mi[qs] - mnew);
            mi[qs] = mnew;
            li[qs] *= alpha;
#pragma unroll
            for (int nt = 0; nt < 4; ++nt)
#pragma unroll
              for (int r = 0; r < 4; ++r) o[qs][nt][r] *= alpha;
          }
        }
        // P = exp2(s*SC - mi) -> per-wave Pt (stride 68) -> B-frag regs;
        // one 16-row Pt buffer reused across qs (in-wave LDS ordering).
        bf16x8 pf[2][2];
#pragma unroll
        for (int qs = 0; qs < 2; ++qs) {
          float rs = 0.f;
#pragma unroll
          for (int nt = 0; nt < 4; ++nt) {
            float p0 = __builtin_amdgcn_exp2f(fmaf(s[qs][nt][0], SC, -mi[qs]));
            float p1 = __builtin_amdgcn_exp2f(fmaf(s[qs][nt][1], SC, -mi[qs]));
            float p2 = __builtin_amdgcn_exp2f(fmaf(s[qs][nt][2], SC, -mi[qs]));
            float p3 = __builtin_amdgcn_exp2f(fmaf(s[qs][nt][3], SC, -mi[qs]));
            rs += (p0 + p1) + (p2 + p3);
            uint2 pk;
            pk.x = cvt_pk_bf16(p0, p1);
            pk.y = cvt_pk_bf16(p2, p3);
            *(uint2*)(&Pt[w][lr * 68 + nt * 16 + lq * 4]) = pk;
          }
          li[qs] += rs;                  // per-lane partial; reduced at end
#pragma unroll
          for (int kb = 0; kb < 2; ++kb) {
            union { uint2 u[2]; bf16x8 v; } pu;
            pu.u[0] = *(const uint2*)(&Pt[w][lr * 68 + kb * 32 + lq * 8]);
            __builtin_amdgcn_sched_barrier(0);
            pu.u[1] = *(const uint2*)(&Pt[w][lr * 68 + kb * 32 + lq * 8 + 4]);
            pf[qs][kb] = pu.v;
          }
        }
        // O^T += V^T P^T (V frags read once, used for both qs)
        __builtin_amdgcn_s_setprio(1);
#pragma unroll
        for (int nt = 0; nt < 4; ++nt) {
          bf16x8 vf0 = *(const bf16x8*)(&Vt[buf][(nt * 16 + lr) * 72 + lq * 8]);
          bf16x8 vf1 = *(const bf16x8*)(&Vt[buf][(nt * 16 + lr) * 72 + 32 + lq * 8]);
#pragma unroll
          for (int qs = 0; qs < 2; ++qs) {
            o[qs][nt] = mfma16(vf0, pf[qs][0], o[qs][nt]);
            o[qs][nt] = mfma16(vf1, pf[qs][1], o[qs][nt]);
          }
        }
        __builtin_amdgcn_s_setprio(0);
      }

      if (jt + 1 < nkv) {
        stage(buf ^ 1);
        if (jt + 2 < nkv) load_tile(jt + 2);
        else if (phase == 0) load_tile(0);
        __syncthreads();
      }
    }

    // epilogue: reduce per-lane li over lq groups, write Y
#pragma unroll
    for (int qs = 0; qs < 2; ++qs) {
      float l = li[qs];
      l += __shfl_xor(l, 16);
      l += __shfl_xor(l, 32);
      float inv = 1.f / l;
      int t_g = qw + qs * 16 + lr;
#pragma unroll
      for (int nt = 0; nt < 4; ++nt) {
        uint2 yv;
        yv.x = cvt_pk_bf16(o[qs][nt][0] * inv, o[qs][nt][1] * inv);
        yv.y = cvt_pk_bf16(o[qs][nt][2] * inv, o[qs][nt][3] * inv);
        *(uint2*)(Y + ((size_t)(b * T + t_g)) * 1024 + h * 64 + nt * 16 + lq * 4) = yv;
      }
    }
  }
}

// ---------------- launch ----------------
extern "C" void kernel_launch(void* const* d_in, const int* in_sizes, int n_in,
                              void* d_out, int out_size, void* d_ws, size_t ws_size,
                              hipStream_t stream) {
  const float* x = (const float*)d_in[0];       // [4,2048,1024]
  const float* qkv_w = (const float*)d_in[1];   // [3072,1024]
  const float* qkv_b = (const float*)d_in[2];   // [3072]
  const float* proj_w = (const float*)d_in[3];  // [1024,1024]
  const float* proj_b = (const float*)d_in[4];  // [1024]
  float* out = (float*)d_out;                   // [4,2048,1024] fp32

  unsigned short* ws = (unsigned short*)d_ws;
  unsigned short* xb = ws;                     // 8388608
  unsigned short* wqkv = xb + 8388608;         // 3145728
  unsigned short* wproj = wqkv + 3145728;      // 1048576
  unsigned short* Qb = wproj + 1048576;        // 8388608 [B,H,T,hd]
  unsigned short* Kb = Qb + 8388608;           // 8388608 [B,H,T,hd]
  unsigned short* Vb = Kb + 8388608;           // 8388608 [B,H,hd,T] (transposed!)
  unsigned short* Yb = Vb + 8388608;           // 8388608 [B*T, C]

  auto* g0 = gemm8<0, 2, 1>;
  auto* g1 = gemm8<1, 1, 1>;
  static bool attr_set = false;
  if (!attr_set) {
    (void)hipFuncSetAttribute((const void*)g0,
                              hipFuncAttributeMaxDynamicSharedMemorySize, 114688);
    (void)hipFuncSetAttribute((const void*)g1,
                              hipFuncAttributeMaxDynamicSharedMemorySize, 98304);
    attr_set = true;
  }

  cvt3_kernel<<<12288, 256, 0, stream>>>(x, xb, qkv_w, wqkv, proj_w, wproj);

  // QKV: M=8192, N=3072, K=1024, BM=256/BN=192 -> grid 32*16=512 (2 EXACT rounds)
  gemm8<0, 2, 1><<<dim3(512), 512, 114688, stream>>>(xb, wqkv, qkv_b, nullptr, Qb,
                                                     Kb, Vb, 8192, 3072, 1024, 16);
  // attn: grid 256 (pair, h, b)
  attn_kernel<<<dim3(4, 16, 4), 512, 0, stream>>>(Qb, Kb, Vb, Yb);
  // proj: M=8192, N=1024, K=1024, BM=256/BN=128 -> grid 32*8=256 (1 exact round)
  gemm8<1, 1, 1><<<dim3(256), 512, 98304, stream>>>(Yb, wproj, proj_b, out, nullptr,
                                                    nullptr, nullptr, 8192, 1024,
                                                    1024, 8);
}

// Round 17
// 236.116 us; speedup vs baseline: 1.0413x; 1.0259x over previous
//
#include <hip/hip_runtime.h>
#include <stdint.h>
#include <math.h>

#define DEVI __device__ __forceinline__

typedef __attribute__((ext_vector_type(8))) short bf16x8;
typedef __attribute__((ext_vector_type(4))) float f32x4;

DEVI unsigned short f2bf(float f) {
  union { float f; unsigned u; } v; v.f = f;
  unsigned u = v.u;
  u += 0x7fffu + ((u >> 16) & 1u);   // round-to-nearest-even
  return (unsigned short)(u >> 16);
}

// pack two f32 -> one dword of 2x bf16 (lo = a, hi = b), RNE; no builtin on gfx950
DEVI unsigned cvt_pk_bf16(float a, float b) {
  unsigned r;
  asm("v_cvt_pk_bf16_f32 %0, %1, %2" : "=v"(r) : "v"(a), "v"(b));
  return r;
}

DEVI f32x4 mfma16(bf16x8 a, bf16x8 b, f32x4 c) {
  return __builtin_amdgcn_mfma_f32_16x16x32_bf16(a, b, c, 0, 0, 0);
}

// async global->LDS, 16 B per lane; LDS dest = wave-uniform base + lane*16
DEVI void gld16(const unsigned short* g, unsigned short* l) {
  __builtin_amdgcn_global_load_lds(
      (const __attribute__((address_space(1))) unsigned int*)(uintptr_t)g,
      (__attribute__((address_space(3))) unsigned int*)(unsigned int)(uintptr_t)l,
      16, 0, 0);
}

#define VMCNT(n) asm volatile("s_waitcnt vmcnt(" #n ")" ::: "memory")
#define BAR()                              \
  do {                                     \
    __builtin_amdgcn_s_barrier();          \
    __builtin_amdgcn_sched_barrier(0);     \
  } while (0)

template <int N> DEVI void vmcntc() {
  static_assert(N >= 0 && N <= 8, "");
  if constexpr (N == 0) VMCNT(0);
  else if constexpr (N == 2) VMCNT(2);
  else if constexpr (N == 3) VMCNT(3);
  else if constexpr (N == 4) VMCNT(4);
}

// ---------------- fp32 -> bf16 convert (3 buffers, one launch) ----------------
__global__ __launch_bounds__(256) void cvt3_kernel(
    const float* __restrict__ a, unsigned short* __restrict__ oa,
    const float* __restrict__ b, unsigned short* __restrict__ ob,
    const float* __restrict__ c, unsigned short* __restrict__ oc) {
  int bid = blockIdx.x;
  const float* in; unsigned short* out; int i;
  if (bid < 8192)       { in = a; out = oa; i = bid; }
  else if (bid < 11264) { in = b; out = ob; i = bid - 8192; }
  else                  { in = c; out = oc; i = bid - 11264; }
  int idx = (i * 256 + (int)threadIdx.x) * 4;
  float4 v = *(const float4*)(in + idx);
  unsigned lo = f2bf(v.x) | ((unsigned)f2bf(v.y) << 16);
  unsigned hi = f2bf(v.z) | ((unsigned)f2bf(v.w) << 16);
  uint2 o; o.x = lo; o.y = hi;
  *(uint2*)(out + idx) = o;
}

// ======== 4-phase GEMM (r6-proven), exact-round grids (r12, verbatim) ======
// BK=64, XOR swizzle (0 conflicts), dbuf, 4-phase counted vmcnt, fragment
// reuse. QKV (2,1): BN=192, grid 512 = 2 exact rounds. proj (1,1): BN=128,
// grid 256 = 1 exact round.
// MODE==0 writes Q,K as [b,h,t,d] and V TRANSPOSED as [b,h,d,t].
template <int MODE, int NTA, int NTB>
__global__ __launch_bounds__(512, 2) void gemm8(
    const unsigned short* __restrict__ A, const unsigned short* __restrict__ Bw,
    const float* __restrict__ bias, float* __restrict__ Cf,
    unsigned short* __restrict__ Qo, unsigned short* __restrict__ Ko,
    unsigned short* __restrict__ Vo, int M, int N, int K, int nbx) {
  constexpr int NTT = NTA + NTB;
  constexpr int WTN = NTT * 16;             // wave N-cols
  constexpr int BN = 4 * WTN;
  constexpr int B_USH = BN * 64;
  constexpr int BUFS = 16384 + B_USH;       // A 32KB + B per buffer (ushorts)
  extern __shared__ unsigned short lds[];
  const int tid = threadIdx.x;
  const int lane = tid & 63;
  const int w = tid >> 6;                   // 0..7
  const int wm = w >> 2, wn = w & 3;
  const int lr = lane & 15, lq = lane >> 4;

  // T1: XCD-aware block swizzle (grid % 8 == 0 for both call sites)
  const int cpx = gridDim.x >> 3;
  const int swz = (blockIdx.x & 7) * cpx + (blockIdx.x >> 3);
  const int bx = swz % nbx, by = swz / nbx;
  const int m0 = by * 256, n0 = bx * BN;

  // staging source coords (swizzle baked into the per-lane global column)
  const int sr = lane >> 3;                       // 0..7 row within chunk
  const int sc = ((lane & 7) ^ sr) << 3;          // swizzled col element
  const unsigned short* pa = A + (size_t)(m0 + sr) * K + sc;
  const unsigned short* pb = Bw + (size_t)(n0 + sr) * K + sc;

  // fragment-read block swizzle offsets (ushorts); row&7 == lr&7 for all frags
  const int bs0 = (lq ^ (lr & 7)) << 3;
  const int bs1 = ((lq + 4) ^ (lr & 7)) << 3;

  f32x4 acc[8][NTT] = {};

  auto sA = [&](int buf, int kt, int c) {
    gld16(pa + (size_t)(c << 3) * K + kt, lds + buf * BUFS + (c << 9));
  };
  auto sB = [&](int buf, int kt, int c) {
    gld16(pb + (size_t)(c << 3) * K + kt, lds + buf * BUFS + 16384 + (c << 9));
  };
  auto sAa = [&](int buf, int kt) { sA(buf, kt, w); sA(buf, kt, 16 + w); };
  auto sAb = [&](int buf, int kt) { sA(buf, kt, 8 + w); sA(buf, kt, 24 + w); };
  auto sBa = [&](int buf, int kt) {
#pragma unroll
    for (int k2 = 0; k2 < NTA; ++k2)
      sB(buf, kt, (w & 3) * NTT * 2 + (w >> 2) * NTA + k2);
  };
  auto sBb = [&](int buf, int kt) {
#pragma unroll
    for (int k2 = 0; k2 < NTB; ++k2)
      sB(buf, kt, (w & 3) * NTT * 2 + NTA * 2 + (w >> 2) * NTB + k2);
  };

#define LDA(A_, mh)                                                          \
  _Pragma("unroll") for (int i = 0; i < 4; ++i) {                            \
    int ar = wm * 128 + (mh) * 64 + i * 16 + lr;                             \
    A_[i][0] = *(const bf16x8*)(As_ + ar * 64 + bs0);                        \
    A_[i][1] = *(const bf16x8*)(As_ + ar * 64 + bs1);                        \
  }
#define LDB(B_, CNT, ntb)                                                    \
  _Pragma("unroll") for (int j = 0; j < (CNT); ++j) {                        \
    int br = wn * WTN + ((ntb) + j) * 16 + lr;                               \
    B_[j][0] = *(const bf16x8*)(Bs_ + br * 64 + bs0);                        \
    B_[j][1] = *(const bf16x8*)(Bs_ + br * 64 + bs1);                        \
  }
#define MM(A_, B_, mh, CNT, ntb)                                             \
  __builtin_amdgcn_s_setprio(1);                                             \
  _Pragma("unroll") for (int i = 0; i < 4; ++i)                              \
    _Pragma("unroll") for (int j = 0; j < (CNT); ++j) {                      \
      acc[(mh) * 4 + i][(ntb) + j] =                                         \
          mfma16(A_[i][0], B_[j][0], acc[(mh) * 4 + i][(ntb) + j]);          \
      acc[(mh) * 4 + i][(ntb) + j] =                                         \
          mfma16(A_[i][1], B_[j][1], acc[(mh) * 4 + i][(ntb) + j]);          \
    }                                                                        \
  __builtin_amdgcn_s_setprio(0);

  // prologue: tile 0 into buf0 (unit order A_a, B_a, B_b, A_b)
  sAa(0, 0); sBa(0, 0); sBb(0, 0); sAb(0, 0);
  vmcntc<NTB + 2>();                 // A_a(0), B_a(0) landed
  BAR();

  const int NT = K >> 6;
  for (int t = 0; t < NT - 1; ++t) {
    const int buf = t & 1, nb = buf ^ 1;
    const int kt = (t + 1) << 6;
    const unsigned short* As_ = lds + buf * BUFS;
    const unsigned short* Bs_ = As_ + 16384;
    bf16x8 af[4][2], baf[NTA][2], bbf[NTB][2];
    // ph1: quadrant (0,a); stage A_a(t+1)
    sAa(nb, kt);
    LDA(af, 0); LDB(baf, NTA, 0);
    MM(af, baf, 0, NTA, 0);
    vmcntc<4>(); BAR();              // B_b(t) landed for all waves
    // ph2: (0,b); stage B_a(t+1); reuse A0
    sBa(nb, kt);
    LDB(bbf, NTB, NTA);
    MM(af, bbf, 0, NTB, NTA);
    vmcntc<NTA + 2>(); BAR();        // A_b(t) landed for all waves
    // ph3: (1,b); stage B_b(t+1); reuse Bb, load A1 (A0 dead)
    sBb(nb, kt);
    LDA(af, 1);
    MM(af, bbf, 1, NTB, NTA);
    // ph4: (1,a); stage A_b(t+1); reuse A1 and Ba — zero ds_reads
    sAb(nb, kt);
    MM(af, baf, 1, NTA, 0);
    vmcntc<NTB + 2>(); BAR();        // A_a(t+1), B_a(t+1) landed
  }
  { // peeled last tile (no staging; same phase order, tighter gates)
    const int buf = (NT - 1) & 1;
    const unsigned short* As_ = lds + buf * BUFS;
    const unsigned short* Bs_ = As_ + 16384;
    bf16x8 af[4][2], baf[NTA][2], bbf[NTB][2];
    LDA(af, 0); LDB(baf, NTA, 0);
    MM(af, baf, 0, NTA, 0);
    vmcntc<2>(); BAR();              // B_b(last) landed
    LDB(bbf, NTB, NTA);
    MM(af, bbf, 0, NTB, NTA);
    vmcntc<0>(); BAR();              // A_b(last) landed
    LDA(af, 1);
    MM(af, bbf, 1, NTB, NTA);
    MM(af, baf, 1, NTA, 0);
  }
#undef LDA
#undef LDB
#undef MM

  // epilogue (wave tile 128 x WTN)
#pragma unroll
  for (int mt = 0; mt < 8; ++mt) {
#pragma unroll
    for (int nt = 0; nt < NTT; ++nt) {
      int n_g = n0 + wn * WTN + nt * 16 + lr;
      float bv = bias[n_g];
      if (MODE == 1) {
#pragma unroll
        for (int r = 0; r < 4; ++r) {
          int m_g = m0 + wm * 128 + mt * 16 + lq * 4 + r;
          Cf[(size_t)m_g * N + n_g] = acc[mt][nt][r] + bv;
        }
      } else {
        int which = n_g >> 10;               // 0:Q 1:K 2:V (wave-uniform)
        int rem = n_g & 1023;
        int h = rem >> 6, d = rem & 63;
        int m_base = m0 + wm * 128 + mt * 16 + lq * 4;
        int b = m_base >> 11, tt = m_base & 2047;
        if (which == 2) {
          uint2 pv;
          pv.x = cvt_pk_bf16(acc[mt][nt][0] + bv, acc[mt][nt][1] + bv);
          pv.y = cvt_pk_bf16(acc[mt][nt][2] + bv, acc[mt][nt][3] + bv);
          *(uint2*)(Vo + (((size_t)(b * 16 + h) * 64 + d) * 2048 + tt)) = pv;
        } else {
          unsigned short* p = (which == 0) ? Qo : Ko;
#pragma unroll
          for (int r = 0; r < 4; ++r) {
            size_t idx = (((size_t)(b * 16 + h) * 2048) + tt + r) * 64 + d;
            p[idx] = f2bf(acc[mt][nt][r] + bv);
          }
        }
      }
    }
  }
}

// ------- flash attention (causal), T15 double-pipeline, 256-row Q-tiles -------
// Round-17: 1-tile software lag. Iteration slot j issues QK^T(j) (results
// consumed NEXT slot) then runs softmax+PV for tile j-1 -> softmax VALU
// overlaps QK^T MFMA latency instead of serially waiting on it (the profile
// was chain-bound: no pipe >42%). K/V in a 3-BUFFER rotation (j%3): readers
// {j, j-1} and staged {j+1} always pairwise distinct -> one barrier per tile.
// WAR on buf (j+1)%3 (held tile j-2) sealed by the previous slot's barrier.
// nkv always even -> unroll-by-2 with named sA/sB (rule #20: no runtime
// s-index). Extra barrier at phase start (phase-1 stage(0) vs phase-0
// epilogue PV read when (nkv-1)%3==0). Pt stride 68 (r16-verified).
__global__ __launch_bounds__(512, 2) void attn_kernel(
    const unsigned short* __restrict__ Q, const unsigned short* __restrict__ K,
    const unsigned short* __restrict__ V, unsigned short* __restrict__ Y) {
  constexpr int T = 2048, HD = 64, H = 16;
  __shared__ unsigned short Kt[3][64 * 72];   // K rows [kv][d], pad 8
  __shared__ unsigned short Vt[3][64 * 72];   // V^T    [d][kv], pad 8
  __shared__ unsigned short Pt[8][16 * 68];   // per-wave P, [q][kv], stride 68

  const int tid = threadIdx.x;
  const int lane = tid & 63;
  const int w = tid >> 6;                     // 0..7
  const int lr = lane & 15, lq = lane >> 4;
  const int pair = blockIdx.x;                // 0..3
  const int h = blockIdx.y;
  const int b = blockIdx.z;
  const size_t bh = (size_t)(b * H + h) * T * HD;   // also V^T base (64*2048)
  const float SC = 0.125f * 1.44269504089f;   // 1/sqrt(64) * log2(e)

  const int krow = tid >> 3, kcb = (tid & 7) << 3;  // 64 rows x 64 cols tile

  float4 kr, vr;
  auto load_tile = [&](int jt) {
    const int c0 = jt * 64;
    kr = *(const float4*)(K + bh + (size_t)(c0 + krow) * HD + kcb);
    vr = *(const float4*)(V + bh + (size_t)krow * T + c0 + kcb);  // V^T row=d
  };
  auto stage = [&](int buf) {
    *(float4*)(&Kt[buf][krow * 72 + kcb]) = kr;
    *(float4*)(&Vt[buf][krow * 72 + kcb]) = vr;
  };

  load_tile(0);

  for (int phase = 0; phase < 2; ++phase) {
    const int qt = phase ? (7 - pair) : pair;
    const int q0 = qt * 256;
    const int nkv = 4 * (qt + 1);        // always even, >= 4
    const int qw = q0 + w * 32;          // wave's first q-row

    bf16x8 qf[2][2];
#pragma unroll
    for (int qs = 0; qs < 2; ++qs)
#pragma unroll
      for (int kb = 0; kb < 2; ++kb)
        qf[qs][kb] = *(const bf16x8*)(Q + bh + (size_t)(qw + qs * 16 + lr) * HD +
                                      kb * 32 + lq * 8);

    f32x4 o[2][4] = {};
    float mi[2] = {-INFINITY, -INFINITY}, li[2] = {0.f, 0.f};

    // S^T = K Q^T into S_ (MFMA only; results consumed one slot later)
    auto qkt = [&](f32x4 (&S_)[2][4], int j) {
      if (j * 64 > qw + 31) return;      // wave-uniform: tile fully masked
      const unsigned short* Kb_ = Kt[j % 3];
      __builtin_amdgcn_s_setprio(1);
#pragma unroll
      for (int nt = 0; nt < 4; ++nt) {
        bf16x8 kf0 = *(const bf16x8*)(Kb_ + (nt * 16 + lr) * 72 + lq * 8);
        bf16x8 kf1 = *(const bf16x8*)(Kb_ + (nt * 16 + lr) * 72 + 32 + lq * 8);
#pragma unroll
        for (int qs = 0; qs < 2; ++qs) {
          f32x4 z = {};
          z = mfma16(kf0, qf[qs][0], z);
          S_[qs][nt] = mfma16(kf1, qf[qs][1], z);
        }
      }
      __builtin_amdgcn_s_setprio(0);
    };

    // mask + online softmax + Pt round-trip + PV for tile jm (S_ from prev slot)
    auto finish = [&](f32x4 (&S_)[2][4], int jm) {
      const int c0m = jm * 64;
      if (c0m > qw + 31) return;
      const unsigned short* Vb_ = Vt[jm % 3];
      if (c0m + 63 > qw) {               // causal mask, diagonal tiles only
#pragma unroll
        for (int qs = 0; qs < 2; ++qs) {
          int qg = qw + qs * 16 + lr;
#pragma unroll
          for (int nt = 0; nt < 4; ++nt)
#pragma unroll
            for (int r = 0; r < 4; ++r) {
              int kvg = c0m + nt * 16 + lq * 4 + r;
              if (kvg > qg) S_[qs][nt][r] = -INFINITY;
            }
        }
      }
      float mxs[2];
#pragma unroll
      for (int qs = 0; qs < 2; ++qs) {
        float mx = -INFINITY;
#pragma unroll
        for (int nt = 0; nt < 4; ++nt)
          mx = fmaxf(mx, fmaxf(fmaxf(S_[qs][nt][0], S_[qs][nt][1]),
                               fmaxf(S_[qs][nt][2], S_[qs][nt][3])));
        mx = fmaxf(mx, __shfl_xor(mx, 16));
        mx = fmaxf(mx, __shfl_xor(mx, 32));
        mxs[qs] = mx * SC;
      }
      if (!__all((mxs[0] <= mi[0] + 8.f) && (mxs[1] <= mi[1] + 8.f))) {
#pragma unroll
        for (int qs = 0; qs < 2; ++qs) {
          float mnew = fmaxf(mi[qs], mxs[qs]);
          float alpha = __builtin_amdgcn_exp2f(mi[qs] - mnew);
          mi[qs] = mnew;
          li[qs] *= alpha;
#pragma unroll
          for (int nt = 0; nt < 4; ++nt)
#pragma unroll
            for (int r = 0; r < 4; ++r) o[qs][nt][r] *= alpha;
        }
      }
      bf16x8 pf[2][2];
#pragma unroll
      for (int qs = 0; qs < 2; ++qs) {
        float rs = 0.f;
#pragma unroll
        for (int nt = 0; nt < 4; ++nt) {
          float p0 = __builtin_amdgcn_exp2f(fmaf(S_[qs][nt][0], SC, -mi[qs]));
          float p1 = __builtin_amdgcn_exp2f(fmaf(S_[qs][nt][1], SC, -mi[qs]));
          float p2 = __builtin_amdgcn_exp2f(fmaf(S_[qs][nt][2], SC, -mi[qs]));
          float p3 = __builtin_amdgcn_exp2f(fmaf(S_[qs][nt][3], SC, -mi[qs]));
          rs += (p0 + p1) + (p2 + p3);
          uint2 pk;
          pk.x = cvt_pk_bf16(p0, p1);
          pk.y = cvt_pk_bf16(p2, p3);
          *(uint2*)(&Pt[w][lr * 68 + nt * 16 + lq * 4]) = pk;
        }
        li[qs] += rs;                    // per-lane partial; reduced at end
#pragma unroll
        for (int kb = 0; kb < 2; ++kb) {
          union { uint2 u[2]; bf16x8 v; } pu;
          pu.u[0] = *(const uint2*)(&Pt[w][lr * 68 + kb * 32 + lq * 8]);
          __builtin_amdgcn_sched_barrier(0);
          pu.u[1] = *(const uint2*)(&Pt[w][lr * 68 + kb * 32 + lq * 8 + 4]);
          pf[qs][kb] = pu.v;
        }
      }
      __builtin_amdgcn_s_setprio(1);
#pragma unroll
      for (int nt = 0; nt < 4; ++nt) {
        bf16x8 vf0 = *(const bf16x8*)(Vb_ + (nt * 16 + lr) * 72 + lq * 8);
        bf16x8 vf1 = *(const bf16x8*)(Vb_ + (nt * 16 + lr) * 72 + 32 + lq * 8);
#pragma unroll
        for (int qs = 0; qs < 2; ++qs) {
          o[qs][nt] = mfma16(vf0, pf[qs][0], o[qs][nt]);
          o[qs][nt] = mfma16(vf1, pf[qs][1], o[qs][nt]);
        }
      }
      __builtin_amdgcn_s_setprio(0);
    };

    __syncthreads();   // seal previous phase's epilogue LDS reads (WAR)
    stage(0);
    load_tile(1);
    __syncthreads();

    f32x4 sA[2][4], sB[2][4];
    for (int j = 0; j < nkv; j += 2) {
      // slot A: QK^T(j); finish(j-1); stage(j+1)
      qkt(sA, j);
      if (j > 0) finish(sB, j - 1);
      stage((j + 1) % 3);
      if (j + 2 < nkv) load_tile(j + 2);
      else if (phase == 0) load_tile(0);   // seam: phase-1's tile 0
      __syncthreads();
      // slot B: QK^T(j+1); finish(j); stage(j+2) unless last pair
      qkt(sB, j + 1);
      finish(sA, j);
      if (j + 2 < nkv) {
        stage((j + 2) % 3);
        load_tile(j + 3);                  // j+3 <= nkv-1 always here
        __syncthreads();
      }
    }
    finish(sB, nkv - 1);

    // epilogue: reduce per-lane li over lq groups, write Y
#pragma unroll
    for (int qs = 0; qs < 2; ++qs) {
      float l = li[qs];
      l += __shfl_xor(l, 16);
      l += __shfl_xor(l, 32);
      float inv = 1.f / l;
      int t_g = qw + qs * 16 + lr;
#pragma unroll
      for (int nt = 0; nt < 4; ++nt) {
        uint2 yv;
        yv.x = cvt_pk_bf16(o[qs][nt][0] * inv, o[qs][nt][1] * inv);
        yv.y = cvt_pk_bf16(o[qs][nt][2] * inv, o[qs][nt][3] * inv);
        *(uint2*)(Y + ((size_t)(b * T + t_g)) * 1024 + h * 64 + nt * 16 + lq * 4) = yv;
      }
    }
  }
}

// ---------------- launch ----------------
extern "C" void kernel_launch(void* const* d_in, const int* in_sizes, int n_in,
                              void* d_out, int out_size, void* d_ws, size_t ws_size,
                              hipStream_t stream) {
  const float* x = (const float*)d_in[0];       // [4,2048,1024]
  const float* qkv_w = (const float*)d_in[1];   // [3072,1024]
  const float* qkv_b = (const float*)d_in[2];   // [3072]
  const float* proj_w = (const float*)d_in[3];  // [1024,1024]
  const float* proj_b = (const float*)d_in[4];  // [1024]
  float* out = (float*)d_out;                   // [4,2048,1024] fp32

  unsigned short* ws = (unsigned short*)d_ws;
  unsigned short* xb = ws;                     // 8388608
  unsigned short* wqkv = xb + 8388608;         // 3145728
  unsigned short* wproj = wqkv + 3145728;      // 1048576
  unsigned short* Qb = wproj + 1048576;        // 8388608 [B,H,T,hd]
  unsigned short* Kb = Qb + 8388608;           // 8388608 [B,H,T,hd]
  unsigned short* Vb = Kb + 8388608;           // 8388608 [B,H,hd,T] (transposed!)
  unsigned short* Yb = Vb + 8388608;           // 8388608 [B*T, C]

  auto* g0 = gemm8<0, 2, 1>;
  auto* g1 = gemm8<1, 1, 1>;
  static bool attr_set = false;
  if (!attr_set) {
    (void)hipFuncSetAttribute((const void*)g0,
                              hipFuncAttributeMaxDynamicSharedMemorySize, 114688);
    (void)hipFuncSetAttribute((const void*)g1,
                              hipFuncAttributeMaxDynamicSharedMemorySize, 98304);
    attr_set = true;
  }

  cvt3_kernel<<<12288, 256, 0, stream>>>(x, xb, qkv_w, wqkv, proj_w, wproj);

  // QKV: M=8192, N=3072, K=1024, BM=256/BN=192 -> grid 32*16=512 (2 EXACT rounds)
  gemm8<0, 2, 1><<<dim3(512), 512, 114688, stream>>>(xb, wqkv, qkv_b, nullptr, Qb,
                                                     Kb, Vb, 8192, 3072, 1024, 16);
  // attn: grid 256 (pair, h, b)
  attn_kernel<<<dim3(4, 16, 4), 512, 0, stream>>>(Qb, Kb, Vb, Yb);
  // proj: M=8192, N=1024, K=1024, BM=256/BN=128 -> grid 32*8=256 (1 exact round)
  gemm8<1, 1, 1><<<dim3(256), 512, 98304, stream>>>(Yb, wproj, proj_b, out, nullptr,
                                                    nullptr, nullptr, 8192, 1024,
                                                    1024, 8);
}